// Round 9
// baseline (130.898 us; speedup 1.0000x reference)
//
#include <hip/hip_runtime.h>
#include <hip/hip_bf16.h>
#include <math.h>

#define D_CH   256
#define NHEAD  4
#define DHEAD  64
#define NPTS   4096
#define KSPLIT 8
#define KCHUNK (NPTS / KSPLIT)          // 512 keys = 8 tiles of 64
#define BN_RSQ 0.99999500003749963f     // 1/sqrt(1 + 1e-5)
#define HSTRIDE 262144                  // 4096*64 ushorts per head

typedef __attribute__((ext_vector_type(4))) float f32x4;
typedef __attribute__((ext_vector_type(8))) short bf16x8;
typedef unsigned short ushort_t;

__device__ __forceinline__ ushort_t f2bf(float x) {
    unsigned int b = __float_as_uint(x);
    return (ushort_t)((b + 0x7FFF + ((b >> 16) & 1)) >> 16);  // RNE
}
__device__ __forceinline__ float bf2f(ushort_t u) {
    return __uint_as_float(((unsigned int)u) << 16);
}
__device__ __forceinline__ unsigned pack2bf(float lo, float hi) {
    return (unsigned)f2bf(lo) | ((unsigned)f2bf(hi) << 16);
}

// ---------------------------------------------------------------------------
// prep: transpose-cast x [256][4096] f32 -> xT [4096][256] bf16
// ---------------------------------------------------------------------------
__global__ __launch_bounds__(256) void transpose_cast(
    const float* __restrict__ x, ushort_t* __restrict__ xT)
{
    __shared__ float xs[64][65];
    const int tid = threadIdx.x;
    const int n0 = blockIdx.x * 64, k0 = blockIdx.y * 64;
#pragma unroll
    for (int p = 0; p < 16; ++p) {
        int kk = p * 4 + (tid >> 6), nn = tid & 63;
        xs[kk][nn] = x[(size_t)(k0 + kk) * NPTS + n0 + nn];
    }
    __syncthreads();
#pragma unroll
    for (int p = 0; p < 16; ++p) {
        int nn = p * 4 + (tid >> 6), kk = tid & 63;
        xT[(size_t)(n0 + nn) * D_CH + k0 + kk] = f2bf(xs[kk][nn]);
    }
}

// ---------------------------------------------------------------------------
// prep: S [4096][4096] f32 -> Sf16 bf16 fragment layout (32 MB):
//   Sf16[(qt*64+kt)*4096 + w*1024 + lane*16 + kb*4 + r]
//     = S[qt*64 + w*16 + (lane&15)][kt*64 + kb*16 + (lane>>4)*4 + r]
// ---------------------------------------------------------------------------
__global__ __launch_bounds__(256) void prep_mask(
    const float* __restrict__ S, ushort_t* __restrict__ Sf16)
{
    __shared__ float lds[64][68];
    const int tid = threadIdx.x;
    const int qt = blockIdx.x, kt = blockIdx.y;
    const float* Sblk = S + (size_t)qt * 64 * NPTS + kt * 64;

#pragma unroll
    for (int p = 0; p < 4; ++p) {
        int slot = p * 256 + tid;
        int row = slot >> 4, col4 = slot & 15;
        f32x4 v = *(const f32x4*)&Sblk[(size_t)row * NPTS + col4 * 4];
        *(f32x4*)&lds[row][col4 * 4] = v;
    }
    __syncthreads();

    const int w = tid >> 6, lane = tid & 63;
    const int q = w * 16 + (lane & 15);
    const int lhi = lane >> 4;
    unsigned out8[8];
#pragma unroll
    for (int jq = 0; jq < 4; ++jq) {
        f32x4 v = *(const f32x4*)&lds[q][jq * 16 + lhi * 4];
        out8[jq * 2]     = pack2bf(v.x, v.y);
        out8[jq * 2 + 1] = pack2bf(v.z, v.w);
    }
    unsigned* dst = (unsigned*)Sf16 + ((size_t)qt * 64 + kt) * 2048 + tid * 8;
    *(uint4*)dst       = make_uint4(out8[0], out8[1], out8[2], out8[3]);
    *(uint4*)(dst + 4) = make_uint4(out8[4], out8[5], out8[6], out8[7]);
}

// ---------------------------------------------------------------------------
// Shared MFMA GEMM tile body: acc[2][2] = sum_k A[m][k]*Bt[n][k]
// ---------------------------------------------------------------------------
__device__ __forceinline__ void gemm_tile_body(
    const float* __restrict__ A, const ushort_t* __restrict__ Bt,
    int K, int m0, int n0, int l15, int lhi, f32x4 acc[2][2])
{
#pragma unroll
    for (int i = 0; i < 2; ++i)
#pragma unroll
        for (int j = 0; j < 2; ++j) acc[i][j] = (f32x4){0.f, 0.f, 0.f, 0.f};

    for (int k0 = 0; k0 < K; k0 += 32) {
        bf16x8 af[2], bfr[2];
#pragma unroll
        for (int mf = 0; mf < 2; ++mf) {
            const float* ap = A + (size_t)(m0 + mf * 16 + l15) * K + k0 + lhi * 8;
            float4 a0 = *(const float4*)ap;
            float4 a1 = *(const float4*)(ap + 4);
            bf16x8 t;
            t[0] = (short)f2bf(a0.x); t[1] = (short)f2bf(a0.y);
            t[2] = (short)f2bf(a0.z); t[3] = (short)f2bf(a0.w);
            t[4] = (short)f2bf(a1.x); t[5] = (short)f2bf(a1.y);
            t[6] = (short)f2bf(a1.z); t[7] = (short)f2bf(a1.w);
            af[mf] = t;
        }
#pragma unroll
        for (int nf = 0; nf < 2; ++nf)
            bfr[nf] = *(const bf16x8*)&Bt[(size_t)(n0 + nf * 16 + l15) * K + k0 + lhi * 8];
#pragma unroll
        for (int mf = 0; mf < 2; ++mf)
#pragma unroll
            for (int nf = 0; nf < 2; ++nf)
                acc[mf][nf] = __builtin_amdgcn_mfma_f32_16x16x32_bf16(af[mf], bfr[nf], acc[mf][nf], 0, 0, 0);
    }
}

// ---------------------------------------------------------------------------
// Fused QKV projection -> fragment-major layouts (0.125 folded into Q).
// ---------------------------------------------------------------------------
__global__ __launch_bounds__(256) void gemm_qkv(
    const float* __restrict__ Wq, const float* __restrict__ bq,
    const float* __restrict__ Wk, const float* __restrict__ bk,
    const float* __restrict__ Wv, const float* __restrict__ bv,
    const ushort_t* __restrict__ xT,
    ushort_t* __restrict__ Qf, ushort_t* __restrict__ Kf, ushort_t* __restrict__ Vf)
{
    const int tid = threadIdx.x;
    const int w = tid >> 6, lane = tid & 63, l15 = lane & 15, lhi = lane >> 4;
    const int wm = w >> 1, wn = w & 1;
    const int m0 = blockIdx.y * 64 + wm * 32;
    const int n0 = blockIdx.x * 64 + wn * 32;
    const int z = blockIdx.z;

    const float* A    = (z == 0) ? Wq : (z == 1) ? Wk : Wv;
    const float* bias = (z == 0) ? bq : (z == 1) ? bk : bv;
    ushort_t* dst     = (z == 0) ? Qf : (z == 1) ? Kf : Vf;
    const float scl   = (z == 0) ? 0.125f : 1.0f;

    f32x4 acc[2][2];
    gemm_tile_body(A, xT, D_CH, m0, n0, l15, lhi, acc);

#pragma unroll
    for (int mf = 0; mf < 2; ++mf) {
#pragma unroll
        for (int r = 0; r < 4; ++r) {
            int m = m0 + mf * 16 + lhi * 4 + r;
            int head = m >> 6, dch = m & 63;
            float bi = bias[m];
#pragma unroll
            for (int nf = 0; nf < 2; ++nf) {
                int n = n0 + nf * 16 + l15;
                float v = (acc[mf][nf][r] + bi) * scl;
                size_t idx;
                if (z < 2)
                    idx = (size_t)head * HSTRIDE + (size_t)(n >> 4) * 1024 + (dch >> 5) * 512
                        + (((dch >> 3) & 3) * 16 + (n & 15)) * 8 + (dch & 7);
                else
                    idx = (size_t)head * HSTRIDE + (size_t)(n >> 6) * 4096 + (dch >> 4) * 1024
                        + ((n >> 5) & 1) * 512 + (((n >> 3) & 3) * 16 + (dch & 15)) * 8 + (n & 7);
                dst[idx] = f2bf(v);
            }
        }
    }
}

// ---------------------------------------------------------------------------
// Generic MFMA GEMM for the MLP chain.
// out_mode: 0 = f32 C[m][n] (+resid);  3 = bf16 transposed Cu[n*M + m]
// ---------------------------------------------------------------------------
__global__ __launch_bounds__(256) void gemm_mfma(
    const float* __restrict__ A, const ushort_t* __restrict__ Bt,
    void* __restrict__ Cout, int M, int N, int K,
    const float* __restrict__ bias, const float* __restrict__ gamma,
    const float* __restrict__ beta, int relu, const float* __restrict__ resid,
    int out_mode)
{
    const int tid = threadIdx.x;
    const int w = tid >> 6, lane = tid & 63, l15 = lane & 15, lhi = lane >> 4;
    const int wm = w >> 1, wn = w & 1;
    const int m0 = blockIdx.y * 64 + wm * 32;
    const int n0 = blockIdx.x * 64 + wn * 32;

    f32x4 acc[2][2];
    gemm_tile_body(A, Bt, K, m0, n0, l15, lhi, acc);

    float* Cf = (float*)Cout;
    ushort_t* Cu = (ushort_t*)Cout;
#pragma unroll
    for (int mf = 0; mf < 2; ++mf) {
#pragma unroll
        for (int r = 0; r < 4; ++r) {
            int m = m0 + mf * 16 + lhi * 4 + r;
            float bi = bias[m];
            float sc = 1.0f, sh = 0.0f;
            if (gamma) { sc = gamma[m] * BN_RSQ; sh = beta[m]; }
#pragma unroll
            for (int nf = 0; nf < 2; ++nf) {
                int n = n0 + nf * 16 + l15;
                float v = acc[mf][nf][r] + bi;
                if (gamma) v = v * sc + sh;
                if (relu)  v = fmaxf(v, 0.0f);
                if (resid) v += resid[(size_t)m * N + n];
                if (out_mode == 0) Cf[(size_t)m * N + n] = v;
                else               Cu[(size_t)n * M + m] = f2bf(v);
            }
        }
    }
}

// ---------------------------------------------------------------------------
// One 64-key tile, no-max softmax, fully pipelined:
//  - K fragments for THIS tile already in registers (kc0/kc1)
//  - prefetch next tile's K into kn0/kn1 and mask into snxt
//  - V issued right after QK (exp+LDS covers its latency)
//  - exp/pack fused per-kb (short live ranges)
// ---------------------------------------------------------------------------
__device__ __forceinline__ void attn_tile(
    int kt, int ktn, const ushort_t* __restrict__ Sfw,
    const ushort_t* __restrict__ Kh, const ushort_t* __restrict__ Vh,
    const bf16x8& qf0, const bf16x8& qf1,
    bf16x8 (&kc0)[4], bf16x8 (&kc1)[4],
    bf16x8 (&kn0)[4], bf16x8 (&kn1)[4],
    bf16x8 (&scur)[2], bf16x8 (&snxt)[2],
    f32x4 (&macc)[4], float& lrun,
    ushort_t (* __restrict__ Pw)[88], int l15, int lhi, int lane)
{
    // prefetch next tile's K fragments + mask (consumed next tile)
    const ushort_t* knp = Kh + (size_t)(ktn * 4) * 1024 + lane * 8;
#pragma unroll
    for (int kb = 0; kb < 4; ++kb) {
        kn0[kb] = *(const bf16x8*)(knp + kb * 1024);
        kn1[kb] = *(const bf16x8*)(knp + kb * 1024 + 512);
    }
    snxt[0] = *(const bf16x8*)&Sfw[(size_t)ktn * 4096];
    snxt[1] = *(const bf16x8*)&Sfw[(size_t)ktn * 4096 + 8];

    // QK^T from registers — no memory wait on the critical path
    f32x4 sacc[4];
#pragma unroll
    for (int kb = 0; kb < 4; ++kb) {
        f32x4 z = (f32x4){0.f, 0.f, 0.f, 0.f};
        z = __builtin_amdgcn_mfma_f32_16x16x32_bf16(kc0[kb], qf0, z, 0, 0, 0);
        z = __builtin_amdgcn_mfma_f32_16x16x32_bf16(kc1[kb], qf1, z, 0, 0, 0);
        sacc[kb] = z;
    }

    // issue V loads now; exp + LDS round-trip (~300cy) covers their latency
    bf16x8 vf[8];
    const ushort_t* vb = Vh + (size_t)kt * 4096 + lane * 8;
#pragma unroll
    for (int mm = 0; mm < 2; ++mm)
#pragma unroll
        for (int db = 0; db < 4; ++db)
            vf[mm * 4 + db] = *(const bf16x8*)(vb + db * 1024 + mm * 512);

    // p = exp(score*mask); accumulate l; pack + LDS write, fused per kb
    float ts = 0.0f;
#pragma unroll
    for (int kb = 0; kb < 4; ++kb) {
        float p0, p1, p2, p3;
        {
            const bf16x8& sc = scur[kb >> 1];
            const int jb = (kb & 1) * 4;
            p0 = __expf(sacc[kb][0] * bf2f((ushort_t)sc[jb]));
            p1 = __expf(sacc[kb][1] * bf2f((ushort_t)sc[jb + 1]));
            p2 = __expf(sacc[kb][2] * bf2f((ushort_t)sc[jb + 2]));
            p3 = __expf(sacc[kb][3] * bf2f((ushort_t)sc[jb + 3]));
        }
        ts += (p0 + p1) + (p2 + p3);
        *(unsigned*)&Pw[l15][kb * 16 + lhi * 4]     = pack2bf(p0, p1);
        *(unsigned*)&Pw[l15][kb * 16 + lhi * 4 + 2] = pack2bf(p2, p3);
    }
    lrun += ts;
    // same-wave RAW through LDS; compiler inserts lgkmcnt wait

    // PV: mfma(A=V row=d, B=P col=q)
#pragma unroll
    for (int mm = 0; mm < 2; ++mm) {
        bf16x8 pf = *(const bf16x8*)&Pw[l15][mm * 32 + lhi * 8];
#pragma unroll
        for (int db = 0; db < 4; ++db)
            macc[db] = __builtin_amdgcn_mfma_f32_16x16x32_bf16(vf[mm * 4 + db], pf, macc[db], 0, 0, 0);
    }
}

// ---------------------------------------------------------------------------
// MFMA flash attention: per-head blocks, key-split 8, fragment-major inputs,
// 2-phase pipelined S *and* K streams, no-max softmax.
// ---------------------------------------------------------------------------
__global__ __launch_bounds__(256, 3) void attn_mfma(
    const ushort_t* __restrict__ Qf, const ushort_t* __restrict__ Kf,
    const ushort_t* __restrict__ Vf, const ushort_t* __restrict__ Sf16,
    ushort_t* __restrict__ pacc, float* __restrict__ pl)
{
    __shared__ __align__(16) ushort_t P_lds[4][16][88];   // 176B rows: ~2-way banks

    const int tid  = threadIdx.x;
    const int w    = tid >> 6;
    const int lane = tid & 63;
    const int l15  = lane & 15;
    const int lhi  = lane >> 4;
    const int h    = blockIdx.y;
    const int ks   = blockIdx.z;
    const int q0   = blockIdx.x * 64 + w * 16;
    const int ktb  = ks * (KCHUNK / 64);

    const ushort_t* Kh = Kf + (size_t)h * HSTRIDE;
    const ushort_t* Vh = Vf + (size_t)h * HSTRIDE;
    const ushort_t* Sfw = Sf16 + (size_t)blockIdx.x * 64 * 4096 + w * 1024 + lane * 16;
    ushort_t (* __restrict__ Pw)[88] = P_lds[w];

    bf16x8 qf0, qf1;
    {
        const ushort_t* qp = Qf + (size_t)h * HSTRIDE + (size_t)(q0 >> 4) * 1024 + lane * 8;
        qf0 = *(const bf16x8*)qp;
        qf1 = *(const bf16x8*)(qp + 512);
    }

    f32x4 macc[4];
#pragma unroll
    for (int db = 0; db < 4; ++db) macc[db] = (f32x4){0.f, 0.f, 0.f, 0.f};
    float lrun = 0.0f;

    // prologue: K + S for tile ktb into the A buffers
    bf16x8 kcA0[4], kcA1[4], kcB0[4], kcB1[4];
    {
        const ushort_t* kp = Kh + (size_t)(ktb * 4) * 1024 + lane * 8;
#pragma unroll
        for (int kb = 0; kb < 4; ++kb) {
            kcA0[kb] = *(const bf16x8*)(kp + kb * 1024);
            kcA1[kb] = *(const bf16x8*)(kp + kb * 1024 + 512);
        }
    }
    bf16x8 sA[2], sB[2];
    sA[0] = *(const bf16x8*)&Sfw[(size_t)ktb * 4096];
    sA[1] = *(const bf16x8*)&Sfw[(size_t)ktb * 4096 + 8];

    // 8 tiles -> 4 pair-iterations (static A/B phases)
    for (int kt = ktb; kt < ktb + 8; kt += 2) {
        const int kt2 = (kt + 2 < ktb + 8) ? kt + 2 : ktb;
        attn_tile(kt,     kt + 1, Sfw, Kh, Vh, qf0, qf1,
                  kcA0, kcA1, kcB0, kcB1, sA, sB, macc, lrun, Pw, l15, lhi, lane);
        attn_tile(kt + 1, kt2,    Sfw, Kh, Vh, qf0, qf1,
                  kcB0, kcB1, kcA0, kcA1, sB, sA, macc, lrun, Pw, l15, lhi, lane);
    }

    // deferred cross-group l reduction (once per block)
    lrun += __shfl_xor(lrun, 16);
    lrun += __shfl_xor(lrun, 32);

    // store unnormalized partials
    const size_t pb = ((size_t)ks * NHEAD + h) * NPTS;
    ushort_t* prow = pacc + (pb + q0 + l15) * DHEAD;
#pragma unroll
    for (int db = 0; db < 4; ++db) {
        *(unsigned*)&prow[db * 16 + lhi * 4]     = pack2bf(macc[db][0], macc[db][1]);
        *(unsigned*)&prow[db * 16 + lhi * 4 + 2] = pack2bf(macc[db][2], macc[db][3]);
    }
    if (lane < 16) pl[pb + q0 + lane] = lrun;
}

// ---------------------------------------------------------------------------
// Merge KSPLIT partials (common scale) -> msgT [N][256] bf16.
// ---------------------------------------------------------------------------
__global__ __launch_bounds__(256) void attn_merge(
    const ushort_t* __restrict__ pacc, const float* __restrict__ pl,
    ushort_t* __restrict__ msgT)
{
    const int h = blockIdx.y;
    const int q = blockIdx.x * 64 + (threadIdx.x >> 2);
    const int d0 = (threadIdx.x & 3) * 16;

    float ls = 0.0f;
#pragma unroll
    for (int ks = 0; ks < KSPLIT; ++ks)
        ls += pl[((size_t)ks * NHEAD + h) * NPTS + q];
    float inv = 1.0f / ls;

    float out[16];
#pragma unroll
    for (int j = 0; j < 16; ++j) out[j] = 0.0f;
#pragma unroll
    for (int ks = 0; ks < KSPLIT; ++ks) {
        const ushort_t* ap = pacc + (((size_t)ks * NHEAD + h) * NPTS + q) * DHEAD + d0;
        bf16x8 v0 = *(const bf16x8*)ap;
        bf16x8 v1 = *(const bf16x8*)(ap + 8);
#pragma unroll
        for (int j = 0; j < 8; ++j) {
            out[j]     += bf2f((ushort_t)v0[j]);
            out[8 + j] += bf2f((ushort_t)v1[j]);
        }
    }
    bf16x8 o0, o1;
#pragma unroll
    for (int j = 0; j < 8; ++j) {
        o0[j] = (short)f2bf(out[j] * inv);
        o1[j] = (short)f2bf(out[8 + j] * inv);
    }
    ushort_t* op = msgT + (size_t)q * D_CH + h * DHEAD + d0;
    *(bf16x8*)op = o0;
    *(bf16x8*)(op + 8) = o1;
}

// ---------------------------------------------------------------------------
extern "C" void kernel_launch(void* const* d_in, const int* in_sizes, int n_in,
                              void* d_out, int out_size, void* d_ws, size_t ws_size,
                              hipStream_t stream) {
    const float* x  = (const float*)d_in[0];
    const float* S  = (const float*)d_in[1];
    const float* Wq = (const float*)d_in[2];
    const float* bq = (const float*)d_in[3];
    const float* Wk = (const float*)d_in[4];
    const float* bk = (const float*)d_in[5];
    const float* Wv = (const float*)d_in[6];
    const float* bv = (const float*)d_in[7];
    const float* W1 = (const float*)d_in[8];
    const float* b1 = (const float*)d_in[9];
    const float* g1 = (const float*)d_in[10];
    const float* be1= (const float*)d_in[11];
    const float* W2 = (const float*)d_in[12];
    const float* b2 = (const float*)d_in[13];
    const float* g2 = (const float*)d_in[14];
    const float* be2= (const float*)d_in[15];
    const float* W3 = (const float*)d_in[16];
    const float* b3 = (const float*)d_in[17];

    char* ws = (char*)d_ws;
    const size_t MB = 1024 * 1024;
    ushort_t* Sf16 = (ushort_t*)(ws);                        // 32 MB bf16 fragment mask
    ushort_t* xT   = (ushort_t*)(ws);                        // 2 MB (dead before prep_mask)
    ushort_t* Qf   = (ushort_t*)(ws + 32 * MB);              // 2 MB
    ushort_t* Kf   = (ushort_t*)(ws + 34 * MB);              // 2 MB
    ushort_t* Vf   = (ushort_t*)(ws + 36 * MB);              // 2 MB
    ushort_t* pacc = (ushort_t*)(ws + 38 * MB);              // 16 MB
    float*    pl   = (float*)   (ws + 54 * MB);              // 512 KB
    ushort_t* msgT = (ushort_t*)(ws + 55 * MB);              // 2 MB
    ushort_t* h1T  = (ushort_t*)(ws + 57 * MB);              // 1 MB
    ushort_t* h2T  = (ushort_t*)(ws + 58 * MB);              // 1 MB

    transpose_cast<<<dim3(64, 4), 256, 0, stream>>>(x, xT);
    gemm_qkv<<<dim3(64, 4, 3), 256, 0, stream>>>(Wq, bq, Wk, bk, Wv, bv, xT, Qf, Kf, Vf);
    prep_mask<<<dim3(64, 64), 256, 0, stream>>>(S, Sf16);

    attn_mfma<<<dim3(64, NHEAD, KSPLIT), 256, 0, stream>>>(Qf, Kf, Vf, Sf16, pacc, pl);
    attn_merge<<<dim3(64, NHEAD), 256, 0, stream>>>(pacc, pl, msgT);

    gemm_mfma<<<dim3(64, 2), 256, 0, stream>>>(W1, msgT, h1T, 128, NPTS, 256, b1, g1, be1, 1, nullptr, 3);
    gemm_mfma<<<dim3(64, 2), 256, 0, stream>>>(W2, h1T, h2T, 128, NPTS, 128, b2, g2, be2, 1, nullptr, 3);
    gemm_mfma<<<dim3(64, 4), 256, 0, stream>>>(W3, h2T, d_out, 256, NPTS, 128, b3, nullptr, nullptr, 0, x, 0);
}

// Round 10
// 108.475 us; speedup vs baseline: 1.2067x; 1.2067x over previous
//
#include <hip/hip_runtime.h>
#include <hip/hip_bf16.h>
#include <math.h>

#define D_CH   256
#define NHEAD  4
#define DHEAD  64
#define NPTS   4096
#define KSPLIT 8
#define KCHUNK (NPTS / KSPLIT)          // 512 keys = 8 tiles of 64
#define BN_RSQ 0.99999500003749963f     // 1/sqrt(1 + 1e-5)
#define HSTRIDE 262144                  // 4096*64 ushorts per head

typedef __attribute__((ext_vector_type(4))) float f32x4;
typedef __attribute__((ext_vector_type(8))) short bf16x8;
typedef unsigned short ushort_t;

__device__ __forceinline__ ushort_t f2bf(float x) {
    unsigned int b = __float_as_uint(x);
    return (ushort_t)((b + 0x7FFF + ((b >> 16) & 1)) >> 16);  // RNE
}
__device__ __forceinline__ float bf2f(ushort_t u) {
    return __uint_as_float(((unsigned int)u) << 16);
}
__device__ __forceinline__ unsigned pack2bf(float lo, float hi) {
    return (unsigned)f2bf(lo) | ((unsigned)f2bf(hi) << 16);
}

// ---------------------------------------------------------------------------
// prep: transpose-cast x [256][4096] f32 -> xT [4096][256] bf16
// ---------------------------------------------------------------------------
__global__ __launch_bounds__(256) void transpose_cast(
    const float* __restrict__ x, ushort_t* __restrict__ xT)
{
    __shared__ float xs[64][65];
    const int tid = threadIdx.x;
    const int n0 = blockIdx.x * 64, k0 = blockIdx.y * 64;
#pragma unroll
    for (int p = 0; p < 16; ++p) {
        int kk = p * 4 + (tid >> 6), nn = tid & 63;
        xs[kk][nn] = x[(size_t)(k0 + kk) * NPTS + n0 + nn];
    }
    __syncthreads();
#pragma unroll
    for (int p = 0; p < 16; ++p) {
        int nn = p * 4 + (tid >> 6), kk = tid & 63;
        xT[(size_t)(n0 + nn) * D_CH + k0 + kk] = f2bf(xs[kk][nn]);
    }
}

// ---------------------------------------------------------------------------
// Shared MFMA GEMM tile body: acc[2][2] = sum_k A[m][k]*Bt[n][k]
// ---------------------------------------------------------------------------
__device__ __forceinline__ void gemm_tile_body(
    const float* __restrict__ A, const ushort_t* __restrict__ Bt,
    int K, int m0, int n0, int l15, int lhi, f32x4 acc[2][2])
{
#pragma unroll
    for (int i = 0; i < 2; ++i)
#pragma unroll
        for (int j = 0; j < 2; ++j) acc[i][j] = (f32x4){0.f, 0.f, 0.f, 0.f};

    for (int k0 = 0; k0 < K; k0 += 32) {
        bf16x8 af[2], bfr[2];
#pragma unroll
        for (int mf = 0; mf < 2; ++mf) {
            const float* ap = A + (size_t)(m0 + mf * 16 + l15) * K + k0 + lhi * 8;
            float4 a0 = *(const float4*)ap;
            float4 a1 = *(const float4*)(ap + 4);
            bf16x8 t;
            t[0] = (short)f2bf(a0.x); t[1] = (short)f2bf(a0.y);
            t[2] = (short)f2bf(a0.z); t[3] = (short)f2bf(a0.w);
            t[4] = (short)f2bf(a1.x); t[5] = (short)f2bf(a1.y);
            t[6] = (short)f2bf(a1.z); t[7] = (short)f2bf(a1.w);
            af[mf] = t;
        }
#pragma unroll
        for (int nf = 0; nf < 2; ++nf)
            bfr[nf] = *(const bf16x8*)&Bt[(size_t)(n0 + nf * 16 + l15) * K + k0 + lhi * 8];
#pragma unroll
        for (int mf = 0; mf < 2; ++mf)
#pragma unroll
            for (int nf = 0; nf < 2; ++nf)
                acc[mf][nf] = __builtin_amdgcn_mfma_f32_16x16x32_bf16(af[mf], bfr[nf], acc[mf][nf], 0, 0, 0);
    }
}

// ---------------------------------------------------------------------------
// Fused QKV projection -> fragment-major layouts (0.125 folded into Q).
// ---------------------------------------------------------------------------
__global__ __launch_bounds__(256) void gemm_qkv(
    const float* __restrict__ Wq, const float* __restrict__ bq,
    const float* __restrict__ Wk, const float* __restrict__ bk,
    const float* __restrict__ Wv, const float* __restrict__ bv,
    const ushort_t* __restrict__ xT,
    ushort_t* __restrict__ Qf, ushort_t* __restrict__ Kf, ushort_t* __restrict__ Vf)
{
    const int tid = threadIdx.x;
    const int w = tid >> 6, lane = tid & 63, l15 = lane & 15, lhi = lane >> 4;
    const int wm = w >> 1, wn = w & 1;
    const int m0 = blockIdx.y * 64 + wm * 32;
    const int n0 = blockIdx.x * 64 + wn * 32;
    const int z = blockIdx.z;

    const float* A    = (z == 0) ? Wq : (z == 1) ? Wk : Wv;
    const float* bias = (z == 0) ? bq : (z == 1) ? bk : bv;
    ushort_t* dst     = (z == 0) ? Qf : (z == 1) ? Kf : Vf;
    const float scl   = (z == 0) ? 0.125f : 1.0f;

    f32x4 acc[2][2];
    gemm_tile_body(A, xT, D_CH, m0, n0, l15, lhi, acc);

#pragma unroll
    for (int mf = 0; mf < 2; ++mf) {
#pragma unroll
        for (int r = 0; r < 4; ++r) {
            int m = m0 + mf * 16 + lhi * 4 + r;
            int head = m >> 6, dch = m & 63;
            float bi = bias[m];
#pragma unroll
            for (int nf = 0; nf < 2; ++nf) {
                int n = n0 + nf * 16 + l15;
                float v = (acc[mf][nf][r] + bi) * scl;
                size_t idx;
                if (z < 2)
                    idx = (size_t)head * HSTRIDE + (size_t)(n >> 4) * 1024 + (dch >> 5) * 512
                        + (((dch >> 3) & 3) * 16 + (n & 15)) * 8 + (dch & 7);
                else
                    idx = (size_t)head * HSTRIDE + (size_t)(n >> 6) * 4096 + (dch >> 4) * 1024
                        + ((n >> 5) & 1) * 512 + (((n >> 3) & 3) * 16 + (dch & 15)) * 8 + (n & 7);
                dst[idx] = f2bf(v);
            }
        }
    }
}

// ---------------------------------------------------------------------------
// Small-tile MFMA GEMM for the MLP chain: block tile 32(M) x 64(N),
// 4 warps (2m x 2n), warp tile 16x32 -> 2-4x the block count of the old
// 64x64 kernel (these GEMMs are latency-bound; parallelism is the lever).
// out_mode: 0 = f32 C[m][n] (+resid);  3 = bf16 transposed Cu[n*M + m]
// ---------------------------------------------------------------------------
__global__ __launch_bounds__(256) void gemm_mfma32(
    const float* __restrict__ A, const ushort_t* __restrict__ Bt,
    void* __restrict__ Cout, int M, int N, int K,
    const float* __restrict__ bias, const float* __restrict__ gamma,
    const float* __restrict__ beta, int relu, const float* __restrict__ resid,
    int out_mode)
{
    const int tid = threadIdx.x;
    const int w = tid >> 6, lane = tid & 63, l15 = lane & 15, lhi = lane >> 4;
    const int wm = w >> 1, wn = w & 1;
    const int m0 = blockIdx.y * 32 + wm * 16;
    const int n0 = blockIdx.x * 64 + wn * 32;

    f32x4 acc[2];
#pragma unroll
    for (int j = 0; j < 2; ++j) acc[j] = (f32x4){0.f, 0.f, 0.f, 0.f};

    for (int k0 = 0; k0 < K; k0 += 32) {
        const float* ap = A + (size_t)(m0 + l15) * K + k0 + lhi * 8;
        float4 a0 = *(const float4*)ap;
        float4 a1 = *(const float4*)(ap + 4);
        bf16x8 af;
        af[0] = (short)f2bf(a0.x); af[1] = (short)f2bf(a0.y);
        af[2] = (short)f2bf(a0.z); af[3] = (short)f2bf(a0.w);
        af[4] = (short)f2bf(a1.x); af[5] = (short)f2bf(a1.y);
        af[6] = (short)f2bf(a1.z); af[7] = (short)f2bf(a1.w);
#pragma unroll
        for (int nf = 0; nf < 2; ++nf) {
            bf16x8 bfr = *(const bf16x8*)&Bt[(size_t)(n0 + nf * 16 + l15) * K + k0 + lhi * 8];
            acc[nf] = __builtin_amdgcn_mfma_f32_16x16x32_bf16(af, bfr, acc[nf], 0, 0, 0);
        }
    }

    float* Cf = (float*)Cout;
    ushort_t* Cu = (ushort_t*)Cout;
#pragma unroll
    for (int r = 0; r < 4; ++r) {
        int m = m0 + lhi * 4 + r;
        float bi = bias[m];
        float sc = 1.0f, sh = 0.0f;
        if (gamma) { sc = gamma[m] * BN_RSQ; sh = beta[m]; }
#pragma unroll
        for (int nf = 0; nf < 2; ++nf) {
            int n = n0 + nf * 16 + l15;
            float v = acc[nf][r] + bi;
            if (gamma) v = v * sc + sh;
            if (relu)  v = fmaxf(v, 0.0f);
            if (resid) v += resid[(size_t)m * N + n];
            if (out_mode == 0) Cf[(size_t)m * N + n] = v;
            else               Cu[(size_t)n * M + m] = f2bf(v);
        }
    }
}

// ---------------------------------------------------------------------------
// One 64-key tile, no-max softmax, in-kernel S staging (T14):
//  - Swc = this tile's mask already in per-warp LDS (f32 [16][68])
//  - issue next tile's 4 coalesced S loads NOW; write them to Swn at tile end
//  - K/V direct fragment-major global loads; exp fused per-kb
// ---------------------------------------------------------------------------
__device__ __forceinline__ void attn_tile(
    int kt, int ktn, const float* __restrict__ Sg,
    const ushort_t* __restrict__ Kh, const ushort_t* __restrict__ Vh,
    const bf16x8& qf0, const bf16x8& qf1,
    float (* __restrict__ Swc)[68], float (* __restrict__ Swn)[68],
    f32x4 (&macc)[4], float& lrun,
    ushort_t (* __restrict__ Pw)[88], int l15, int lhi, int lane)
{
    // T14 issue-early: next tile's mask, coalesced (4 rows x 256B per instr)
    f32x4 sr0 = *(const f32x4*)&Sg[(size_t)ktn * 64];
    f32x4 sr1 = *(const f32x4*)&Sg[(size_t)ktn * 64 + 16384];
    f32x4 sr2 = *(const f32x4*)&Sg[(size_t)ktn * 64 + 32768];
    f32x4 sr3 = *(const f32x4*)&Sg[(size_t)ktn * 64 + 49152];

    // QK^T swapped: sacc[kb][r] = score[key=kb*16+lhi*4+r][q=l15]
    f32x4 sacc[4];
#pragma unroll
    for (int kb = 0; kb < 4; ++kb) {
        const ushort_t* kp = Kh + (size_t)(kt * 4 + kb) * 1024 + lane * 8;
        bf16x8 kf0 = *(const bf16x8*)kp;
        bf16x8 kf1 = *(const bf16x8*)(kp + 512);
        f32x4 z = (f32x4){0.f, 0.f, 0.f, 0.f};
        z = __builtin_amdgcn_mfma_f32_16x16x32_bf16(kf0, qf0, z, 0, 0, 0);
        z = __builtin_amdgcn_mfma_f32_16x16x32_bf16(kf1, qf1, z, 0, 0, 0);
        sacc[kb] = z;
    }

    // issue V loads; exp + LDS round-trip covers their latency
    bf16x8 vf[8];
    const ushort_t* vb = Vh + (size_t)kt * 4096 + lane * 8;
#pragma unroll
    for (int mm = 0; mm < 2; ++mm)
#pragma unroll
        for (int db = 0; db < 4; ++db)
            vf[mm * 4 + db] = *(const bf16x8*)(vb + db * 1024 + mm * 512);

    // p = exp(score * mask_f32); accumulate l; pack -> P_lds, fused per kb
    float ts = 0.0f;
#pragma unroll
    for (int kb = 0; kb < 4; ++kb) {
        f32x4 mv = *(const f32x4*)&Swc[l15][kb * 16 + lhi * 4];
        float p0 = __expf(sacc[kb][0] * mv[0]);
        float p1 = __expf(sacc[kb][1] * mv[1]);
        float p2 = __expf(sacc[kb][2] * mv[2]);
        float p3 = __expf(sacc[kb][3] * mv[3]);
        ts += (p0 + p1) + (p2 + p3);
        *(unsigned*)&Pw[l15][kb * 16 + lhi * 4]     = pack2bf(p0, p1);
        *(unsigned*)&Pw[l15][kb * 16 + lhi * 4 + 2] = pack2bf(p2, p3);
    }
    lrun += ts;

    // PV: mfma(A=V row=d, B=P col=q)
#pragma unroll
    for (int mm = 0; mm < 2; ++mm) {
        bf16x8 pf = *(const bf16x8*)&Pw[l15][mm * 32 + lhi * 8];
#pragma unroll
        for (int db = 0; db < 4; ++db)
            macc[db] = __builtin_amdgcn_mfma_f32_16x16x32_bf16(vf[mm * 4 + db], pf, macc[db], 0, 0, 0);
    }

    // T14 write-late: stage next tile's mask into the other buffer
    *(f32x4*)&Swn[lhi][l15 * 4]      = sr0;
    *(f32x4*)&Swn[4 + lhi][l15 * 4]  = sr1;
    *(f32x4*)&Swn[8 + lhi][l15 * 4]  = sr2;
    *(f32x4*)&Swn[12 + lhi][l15 * 4] = sr3;
}

// ---------------------------------------------------------------------------
// MFMA flash attention: per-head blocks, key-split 8, fragment-major K/V,
// raw row-major S staged in per-warp double-buffered LDS, no-max softmax.
// ---------------------------------------------------------------------------
__global__ __launch_bounds__(256, 3) void attn_mfma(
    const ushort_t* __restrict__ Qf, const ushort_t* __restrict__ Kf,
    const ushort_t* __restrict__ Vf, const float* __restrict__ S,
    ushort_t* __restrict__ pacc, float* __restrict__ pl)
{
    __shared__ __align__(16) ushort_t P_lds[4][16][88];
    __shared__ __align__(16) float S_lds[4][2][16][68];   // per-warp dbuf mask

    const int tid  = threadIdx.x;
    const int w    = tid >> 6;
    const int lane = tid & 63;
    const int l15  = lane & 15;
    const int lhi  = lane >> 4;
    const int h    = blockIdx.y;
    const int ks   = blockIdx.z;
    const int q0   = blockIdx.x * 64 + w * 16;
    const int ktb  = ks * (KCHUNK / 64);

    const ushort_t* Kh = Kf + (size_t)h * HSTRIDE;
    const ushort_t* Vh = Vf + (size_t)h * HSTRIDE;
    // lane-based S pointer: row q0+lhi (+4p via 16384 stride), col l15*4 (+kt*64)
    const float* Sg = S + (size_t)(q0 + lhi) * NPTS + l15 * 4;
    ushort_t (* __restrict__ Pw)[88] = P_lds[w];
    float (* __restrict__ Sw0)[68] = S_lds[w][0];
    float (* __restrict__ Sw1)[68] = S_lds[w][1];

    bf16x8 qf0, qf1;
    {
        const ushort_t* qp = Qf + (size_t)h * HSTRIDE + (size_t)(q0 >> 4) * 1024 + lane * 8;
        qf0 = *(const bf16x8*)qp;
        qf1 = *(const bf16x8*)(qp + 512);
    }

    f32x4 macc[4];
#pragma unroll
    for (int db = 0; db < 4; ++db) macc[db] = (f32x4){0.f, 0.f, 0.f, 0.f};
    float lrun = 0.0f;

    // prologue: stage tile ktb into Sw0
    {
        f32x4 t0 = *(const f32x4*)&Sg[(size_t)ktb * 64];
        f32x4 t1 = *(const f32x4*)&Sg[(size_t)ktb * 64 + 16384];
        f32x4 t2 = *(const f32x4*)&Sg[(size_t)ktb * 64 + 32768];
        f32x4 t3 = *(const f32x4*)&Sg[(size_t)ktb * 64 + 49152];
        *(f32x4*)&Sw0[lhi][l15 * 4]      = t0;
        *(f32x4*)&Sw0[4 + lhi][l15 * 4]  = t1;
        *(f32x4*)&Sw0[8 + lhi][l15 * 4]  = t2;
        *(f32x4*)&Sw0[12 + lhi][l15 * 4] = t3;
    }

    // 8 tiles -> 4 pair-iterations (static A/B LDS buffers)
    for (int kt = ktb; kt < ktb + 8; kt += 2) {
        const int kt2 = (kt + 2 < ktb + 8) ? kt + 2 : ktb;
        attn_tile(kt,     kt + 1, Sg, Kh, Vh, qf0, qf1, Sw0, Sw1, macc, lrun, Pw, l15, lhi, lane);
        attn_tile(kt + 1, kt2,    Sg, Kh, Vh, qf0, qf1, Sw1, Sw0, macc, lrun, Pw, l15, lhi, lane);
    }

    // deferred cross-group l reduction (once per block)
    lrun += __shfl_xor(lrun, 16);
    lrun += __shfl_xor(lrun, 32);

    // store unnormalized partials
    const size_t pb = ((size_t)ks * NHEAD + h) * NPTS;
    ushort_t* prow = pacc + (pb + q0 + l15) * DHEAD;
#pragma unroll
    for (int db = 0; db < 4; ++db) {
        *(unsigned*)&prow[db * 16 + lhi * 4]     = pack2bf(macc[db][0], macc[db][1]);
        *(unsigned*)&prow[db * 16 + lhi * 4 + 2] = pack2bf(macc[db][2], macc[db][3]);
    }
    if (lane < 16) pl[pb + q0 + lane] = lrun;
}

// ---------------------------------------------------------------------------
// Merge KSPLIT partials (common scale) -> msgT [N][256] bf16.
// ---------------------------------------------------------------------------
__global__ __launch_bounds__(256) void attn_merge(
    const ushort_t* __restrict__ pacc, const float* __restrict__ pl,
    ushort_t* __restrict__ msgT)
{
    const int h = blockIdx.y;
    const int q = blockIdx.x * 64 + (threadIdx.x >> 2);
    const int d0 = (threadIdx.x & 3) * 16;

    float ls = 0.0f;
#pragma unroll
    for (int ks = 0; ks < KSPLIT; ++ks)
        ls += pl[((size_t)ks * NHEAD + h) * NPTS + q];
    float inv = 1.0f / ls;

    float out[16];
#pragma unroll
    for (int j = 0; j < 16; ++j) out[j] = 0.0f;
#pragma unroll
    for (int ks = 0; ks < KSPLIT; ++ks) {
        const ushort_t* ap = pacc + (((size_t)ks * NHEAD + h) * NPTS + q) * DHEAD + d0;
        bf16x8 v0 = *(const bf16x8*)ap;
        bf16x8 v1 = *(const bf16x8*)(ap + 8);
#pragma unroll
        for (int j = 0; j < 8; ++j) {
            out[j]     += bf2f((ushort_t)v0[j]);
            out[8 + j] += bf2f((ushort_t)v1[j]);
        }
    }
    bf16x8 o0, o1;
#pragma unroll
    for (int j = 0; j < 8; ++j) {
        o0[j] = (short)f2bf(out[j] * inv);
        o1[j] = (short)f2bf(out[8 + j] * inv);
    }
    ushort_t* op = msgT + (size_t)q * D_CH + h * DHEAD + d0;
    *(bf16x8*)op = o0;
    *(bf16x8*)(op + 8) = o1;
}

// ---------------------------------------------------------------------------
extern "C" void kernel_launch(void* const* d_in, const int* in_sizes, int n_in,
                              void* d_out, int out_size, void* d_ws, size_t ws_size,
                              hipStream_t stream) {
    const float* x  = (const float*)d_in[0];
    const float* S  = (const float*)d_in[1];
    const float* Wq = (const float*)d_in[2];
    const float* bq = (const float*)d_in[3];
    const float* Wk = (const float*)d_in[4];
    const float* bk = (const float*)d_in[5];
    const float* Wv = (const float*)d_in[6];
    const float* bv = (const float*)d_in[7];
    const float* W1 = (const float*)d_in[8];
    const float* b1 = (const float*)d_in[9];
    const float* g1 = (const float*)d_in[10];
    const float* be1= (const float*)d_in[11];
    const float* W2 = (const float*)d_in[12];
    const float* b2 = (const float*)d_in[13];
    const float* g2 = (const float*)d_in[14];
    const float* be2= (const float*)d_in[15];
    const float* W3 = (const float*)d_in[16];
    const float* b3 = (const float*)d_in[17];

    char* ws = (char*)d_ws;
    const size_t MB = 1024 * 1024;
    ushort_t* xT   = (ushort_t*)(ws);                        // 2 MB
    ushort_t* Qf   = (ushort_t*)(ws + 2 * MB);               // 2 MB
    ushort_t* Kf   = (ushort_t*)(ws + 4 * MB);               // 2 MB
    ushort_t* Vf   = (ushort_t*)(ws + 6 * MB);               // 2 MB
    ushort_t* pacc = (ushort_t*)(ws + 8 * MB);               // 16 MB
    float*    pl   = (float*)   (ws + 24 * MB);              // 512 KB
    ushort_t* msgT = (ushort_t*)(ws + 25 * MB);              // 2 MB
    ushort_t* h1T  = (ushort_t*)(ws + 27 * MB);              // 1 MB
    ushort_t* h2T  = (ushort_t*)(ws + 28 * MB);              // 1 MB

    transpose_cast<<<dim3(64, 4), 256, 0, stream>>>(x, xT);
    gemm_qkv<<<dim3(64, 4, 3), 256, 0, stream>>>(Wq, bq, Wk, bk, Wv, bv, xT, Qf, Kf, Vf);

    attn_mfma<<<dim3(64, NHEAD, KSPLIT), 256, 0, stream>>>(Qf, Kf, Vf, S, pacc, pl);
    attn_merge<<<dim3(64, NHEAD), 256, 0, stream>>>(pacc, pl, msgT);

    gemm_mfma32<<<dim3(64, 4), 256, 0, stream>>>(W1, msgT, h1T, 128, NPTS, 256, b1, g1, be1, 1, nullptr, 3);
    gemm_mfma32<<<dim3(64, 4), 256, 0, stream>>>(W2, h1T, h2T, 128, NPTS, 128, b2, g2, be2, 1, nullptr, 3);
    gemm_mfma32<<<dim3(64, 8), 256, 0, stream>>>(W3, h2T, d_out, 256, NPTS, 128, b3, nullptr, nullptr, 0, x, 0);
}